// Round 8
// baseline (319.013 us; speedup 1.0000x reference)
//
#include <hip/hip_runtime.h>
#include <hip/hip_bf16.h>

// B=8, N=128, M=256, E=256, De=64, H=8, D=32
#define INV_SCALE 0.17677669529663687f
#define LN_EPS 1e-5f

typedef unsigned int uint;
typedef unsigned short ushort;

__device__ __forceinline__ float blo(uint u) { return __uint_as_float(u << 16); }
__device__ __forceinline__ float bhi(uint u) { return __uint_as_float(u & 0xffff0000u); }
__device__ __forceinline__ ushort bfround(float f) {
  uint u = __float_as_uint(f);
  u += 0x7fffu + ((u >> 16) & 1u);
  return (ushort)(u >> 16);
}
__device__ __forceinline__ uint pkbf(float a, float b) {
  uint ua = __float_as_uint(a); ua += 0x7fffu + ((ua >> 16) & 1u);
  uint ub = __float_as_uint(b); ub += 0x7fffu + ((ub >> 16) & 1u);
  return (ua >> 16) | (ub & 0xffff0000u);
}
__device__ __forceinline__ float bs(ushort u) { return __uint_as_float(((uint)u) << 16); }

// ---------------- Kernel 1: Q/K/V projections + qep fold ----------------
// blk <128: Q -> Qb (bf16) + qepb; <384: K->Kb; <640: V->Vb. All row-major [row][e].
__global__ __launch_bounds__(256) void proj3_kernel(
    const float* __restrict__ q, const float* __restrict__ k, const float* __restrict__ v,
    const float* __restrict__ wq, const float* __restrict__ wk, const float* __restrict__ wv,
    const float* __restrict__ ep_w,
    ushort* __restrict__ Qb, ushort* __restrict__ Kb, ushort* __restrict__ Vb,
    ushort* __restrict__ qepb) {
  constexpr int RPB = 8;
  __shared__ float in_s[RPB][256];
  int blk = blockIdx.x;
  int t = threadIdx.x;
  const float* in; const float* w; int r0;
  if (blk < 128)      { in = q; w = wq; r0 = blk * RPB; }
  else if (blk < 384) { in = k; w = wk; r0 = (blk - 128) * RPB; }
  else                { in = v; w = wv; r0 = (blk - 384) * RPB; }
  #pragma unroll
  for (int r = 0; r < RPB; ++r) in_s[r][t] = in[(size_t)(r0 + r) * 256 + t];
  __syncthreads();
  float acc[RPB];
  #pragma unroll
  for (int r = 0; r < RPB; ++r) acc[r] = 0.f;
  const float4* wrow = reinterpret_cast<const float4*>(w + (size_t)t * 256);
  for (int j4 = 0; j4 < 64; ++j4) {
    float4 wv4 = wrow[j4];
    #pragma unroll
    for (int r = 0; r < RPB; ++r) {
      float4 iv = *reinterpret_cast<const float4*>(&in_s[r][j4 * 4]);
      acc[r] += wv4.x * iv.x + wv4.y * iv.y + wv4.z * iv.z + wv4.w * iv.w;
    }
  }
  if (blk < 128) {
    #pragma unroll
    for (int r = 0; r < RPB; ++r) Qb[(size_t)(r0 + r) * 256 + t] = bfround(acc[r]);
    // fold qep: qep[bn][h][de] = sum_d Qp[bn][h*32+d] * ep_w[(h*32+d)][de]
    __syncthreads();
    #pragma unroll
    for (int r = 0; r < RPB; ++r) in_s[r][t] = acc[r];
    __syncthreads();
    #pragma unroll
    for (int rep = 0; rep < 16; ++rep) {
      int idx = rep * 256 + t;
      int r = idx >> 9, hd = idx & 511;
      int h = hd >> 6, de = hd & 63;
      float s = 0.f;
      #pragma unroll
      for (int d = 0; d < 32; ++d)
        s += in_s[r][h * 32 + d] * ep_w[(size_t)(h * 32 + d) * 64 + de];
      qepb[(size_t)(r0 + r) * 512 + hd] = bfround(s);
    }
  } else if (blk < 384) {
    #pragma unroll
    for (int r = 0; r < RPB; ++r) Kb[(size_t)(r0 + r) * 256 + t] = bfround(acc[r]);
  } else {
    #pragma unroll
    for (int r = 0; r < RPB; ++r) Vb[(size_t)(r0 + r) * 256 + t] = bfround(acc[r]);
  }
}

// ---------------- Kernel 2: barrier-free VALU partial attention ----------------
// grid 2048 = (b:8, ng:32, mc:8). 256 thr = 4 waves; LDS strictly wave-private,
// NO __syncthreads. Wave w: bn = b*128+ng*4+w, m-chunk mc (32 m).
// K/V read direct from global (L1/L2-hot: 16KB chunks shared by 32 blocks).
// Unnormalized exp (scores O(0.1)); partials additive across mc (r3/r4-proven).
__global__ __launch_bounds__(256, 5) void attn_part_kernel(
    const ushort* __restrict__ Qb, const ushort* __restrict__ Kb,
    const ushort* __restrict__ Vb, const ushort* __restrict__ qepb,
    const float* __restrict__ edge,
    ushort* __restrict__ ctxVp, ushort* __restrict__ attEp, float* __restrict__ S_p) {
  __shared__ ushort edge_s[4][32][72];  // [m][de] bf16, 72-pad (r4: 0 conflicts)
  __shared__ float  p_s[4][8][33];      // [h][m]
  __shared__ float  Q_s[4][256];        // fp32 Q row
  __shared__ ushort qep_s[4][512];      // bf16 [h][de]

  const int bid = blockIdx.x;
  const int b = bid >> 8, ng = (bid >> 3) & 31, mc = bid & 7;
  const int t = threadIdx.x;
  const int w = t >> 6, l = t & 63;
  const int bn = b * 128 + ng * 4 + w;
  const int m0 = mc * 32;
  const size_t pidx = (size_t)bn * 8 + mc;

  // ---- stage Q (unpack to fp32) + qep (bf16), wave-private ----
  if (l < 32) {
    uint4 qv = *(const uint4*)(Qb + (size_t)bn * 256 + l * 8);
    float* dst = &Q_s[w][l * 8];
    dst[0] = blo(qv.x); dst[1] = bhi(qv.x); dst[2] = blo(qv.y); dst[3] = bhi(qv.y);
    dst[4] = blo(qv.z); dst[5] = bhi(qv.z); dst[6] = blo(qv.w); dst[7] = bhi(qv.w);
  }
  *(uint4*)&qep_s[w][l * 8] = *(const uint4*)(qepb + (size_t)bn * 512 + l * 8);

  // ---- stage edge chunk fp32 -> bf16, wave-private, coalesced ----
  {
    const float* ebase = edge + ((size_t)bn * 256 + m0) * 64;
    #pragma unroll
    for (int i = 0; i < 8; ++i) {
      int idx = i * 64 + l;
      int m = idx >> 4, de0 = (idx & 15) * 4;
      float4 ev = *(const float4*)(ebase + (size_t)m * 64 + de0);
      uint2 u; u.x = pkbf(ev.x, ev.y); u.y = pkbf(ev.z, ev.w);
      *(uint2*)&edge_s[w][m][de0] = u;
    }
  }

  // ---- scores + exp: lane = (mi = l&31, hg = l>>5), 4 heads each ----
  const int mi = l & 31, hg = l >> 5;
  {
    float acc[4];
    const ushort* krow = Kb + ((size_t)(b * 256 + m0 + mi)) * 256 + hg * 128;
    #pragma unroll
    for (int j = 0; j < 4; ++j) {
      const float* qrow = &Q_s[w][(hg * 4 + j) * 32];
      float s = 0.f;
      #pragma unroll
      for (int d8 = 0; d8 < 4; ++d8) {
        uint4 k8 = *(const uint4*)(krow + j * 32 + d8 * 8);
        const float* qv = qrow + d8 * 8;
        s += blo(k8.x) * qv[0] + bhi(k8.x) * qv[1]
           + blo(k8.y) * qv[2] + bhi(k8.y) * qv[3]
           + blo(k8.z) * qv[4] + bhi(k8.z) * qv[5]
           + blo(k8.w) * qv[6] + bhi(k8.w) * qv[7];
      }
      acc[j] = s;
    }
    #pragma unroll
    for (int de8 = 0; de8 < 8; ++de8) {
      uint4 e8 = *(const uint4*)&edge_s[w][mi][de8 * 8];
      float ef0 = blo(e8.x), ef1 = bhi(e8.x), ef2 = blo(e8.y), ef3 = bhi(e8.y);
      float ef4 = blo(e8.z), ef5 = bhi(e8.z), ef6 = blo(e8.w), ef7 = bhi(e8.w);
      #pragma unroll
      for (int j = 0; j < 4; ++j) {
        uint4 a8 = *(const uint4*)&qep_s[w][(hg * 4 + j) * 64 + de8 * 8];
        acc[j] += ef0 * blo(a8.x) + ef1 * bhi(a8.x) + ef2 * blo(a8.y) + ef3 * bhi(a8.y)
                + ef4 * blo(a8.z) + ef5 * bhi(a8.z) + ef6 * blo(a8.w) + ef7 * bhi(a8.w);
      }
    }
    #pragma unroll
    for (int j = 0; j < 4; ++j) {
      float p = __expf(acc[j] * INV_SCALE);
      p_s[w][hg * 4 + j][mi] = p;
      float sv = p;
      #pragma unroll
      for (int ofs = 1; ofs <= 16; ofs <<= 1) sv += __shfl_xor(sv, ofs);
      if (mi == 0) S_p[pidx * 8 + hg * 4 + j] = sv;
    }
  }

  // ---- PV + attnE accumulate: lane = (h = l>>3, qd = l&7) ----
  {
    const int h = l >> 3, qd = l & 7;
    const int d0 = qd * 4, de0 = qd * 8;
    float at[8] = {0, 0, 0, 0, 0, 0, 0, 0};
    float cv0 = 0, cv1 = 0, cv2 = 0, cv3 = 0;
    const ushort* vcol = Vb + ((size_t)(b * 256 + m0)) * 256 + h * 32 + d0;
    #pragma unroll
    for (int m = 0; m < 32; ++m) {
      float p = p_s[w][h][m];
      uint4 e8 = *(const uint4*)&edge_s[w][m][de0];
      at[0] += p * blo(e8.x); at[1] += p * bhi(e8.x);
      at[2] += p * blo(e8.y); at[3] += p * bhi(e8.y);
      at[4] += p * blo(e8.z); at[5] += p * bhi(e8.z);
      at[6] += p * blo(e8.w); at[7] += p * bhi(e8.w);
      uint2 v4 = *(const uint2*)(vcol + (size_t)m * 256);
      cv0 += p * blo(v4.x); cv1 += p * bhi(v4.x);
      cv2 += p * blo(v4.y); cv3 += p * bhi(v4.y);
    }
    uint4 st; st.x = pkbf(at[0], at[1]); st.y = pkbf(at[2], at[3]);
    st.z = pkbf(at[4], at[5]); st.w = pkbf(at[6], at[7]);
    *(uint4*)(attEp + pidx * 512 + l * 8) = st;
    uint2 sc; sc.x = pkbf(cv0, cv1); sc.y = pkbf(cv2, cv3);
    *(uint2*)(ctxVp + pidx * 256 + l * 4) = sc;
  }
}

// ---------------- Kernel 3: reduce partials + ep fold + out-proj + LN ----------------
// grid 512 x 256 thr; block = 2 bn rows (r4-proven).
__global__ __launch_bounds__(256) void reduce_outln_kernel(
    const ushort* __restrict__ ctxVp, const ushort* __restrict__ attEp,
    const float* __restrict__ S_p, const float* __restrict__ ep_w,
    const float* __restrict__ ep_b, const float* __restrict__ wo_w,
    const float* __restrict__ wo_b, const float* __restrict__ qin,
    const float* __restrict__ ln_g, const float* __restrict__ ln_b,
    float* __restrict__ out) {
  __shared__ float aE_s[2][512];
  __shared__ float ctx_s[2][256];
  __shared__ float o_s[2][256];
  __shared__ float rs_s[2][8];
  int bn0 = blockIdx.x * 2;
  int t = threadIdx.x;
  float cv[2];
  #pragma unroll
  for (int r = 0; r < 2; ++r) {
    float a0 = 0, a1 = 0, cc = 0;
    #pragma unroll
    for (int mcc = 0; mcc < 8; ++mcc) {
      size_t base = (size_t)(bn0 + r) * 8 + mcc;
      a0 += bs(attEp[base * 512 + t]);
      a1 += bs(attEp[base * 512 + 256 + t]);
      cc += bs(ctxVp[base * 256 + t]);
    }
    aE_s[r][t] = a0; aE_s[r][256 + t] = a1; cv[r] = cc;
  }
  if (t < 16) {
    int r = t >> 3, h = t & 7;
    float s = 0.f;
    #pragma unroll
    for (int mcc = 0; mcc < 8; ++mcc)
      s += S_p[((size_t)(bn0 + r) * 8 + mcc) * 8 + h];
    rs_s[r][h] = 1.f / s;
  }
  __syncthreads();
  {
    int h = t >> 5;
    const float* wrow = ep_w + (size_t)t * 64;
    float acc[2] = {0.f, 0.f};
    #pragma unroll
    for (int de4 = 0; de4 < 16; ++de4) {
      float4 w4 = *(const float4*)(wrow + de4 * 4);
      #pragma unroll
      for (int r = 0; r < 2; ++r) {
        float4 a4 = *(const float4*)&aE_s[r][h * 64 + de4 * 4];
        acc[r] += w4.x * a4.x + w4.y * a4.y + w4.z * a4.z + w4.w * a4.w;
      }
    }
    #pragma unroll
    for (int r = 0; r < 2; ++r)
      ctx_s[r][t] = (cv[r] + acc[r]) * rs_s[r][h] + ep_b[t];
  }
  __syncthreads();
  {
    const float4* wrow = (const float4*)(wo_w + (size_t)t * 256);
    float acc[2] = {0.f, 0.f};
    for (int j4 = 0; j4 < 64; ++j4) {
      float4 w4 = wrow[j4];
      #pragma unroll
      for (int r = 0; r < 2; ++r) {
        float4 iv = *(const float4*)&ctx_s[r][j4 * 4];
        acc[r] += w4.x * iv.x + w4.y * iv.y + w4.z * iv.z + w4.w * iv.w;
      }
    }
    float bias = wo_b[t];
    #pragma unroll
    for (int r = 0; r < 2; ++r)
      o_s[r][t] = acc[r] + bias + qin[(size_t)(bn0 + r) * 256 + t];
  }
  __syncthreads();
  {
    int wv = t >> 6, l = t & 63;
    if (wv < 2) {
      int r = wv;
      float sum = 0.f, sq = 0.f;
      #pragma unroll
      for (int kk = 0; kk < 4; ++kk) {
        float x = o_s[r][l + kk * 64];
        sum += x; sq += x * x;
      }
      #pragma unroll
      for (int ofs = 32; ofs; ofs >>= 1) {
        sum += __shfl_xor(sum, ofs);
        sq  += __shfl_xor(sq, ofs);
      }
      float mu = sum * (1.f / 256.f);
      float var = sq * (1.f / 256.f) - mu * mu;
      float rstd = rsqrtf(var + LN_EPS);
      #pragma unroll
      for (int kk = 0; kk < 4; ++kk) {
        int e = l + kk * 64;
        float x = o_s[r][e];
        out[(size_t)(bn0 + r) * 256 + e] = (x - mu) * rstd * ln_g[e] + ln_b[e];
      }
    }
  }
}

extern "C" void kernel_launch(void* const* d_in, const int* in_sizes, int n_in,
                              void* d_out, int out_size, void* d_ws, size_t ws_size,
                              hipStream_t stream) {
  const float* q    = (const float*)d_in[0];
  const float* k    = (const float*)d_in[1];
  const float* v    = (const float*)d_in[2];
  const float* edge = (const float*)d_in[3];
  const float* wq   = (const float*)d_in[4];
  const float* wk   = (const float*)d_in[5];
  const float* wv   = (const float*)d_in[6];
  const float* wo_w = (const float*)d_in[7];
  const float* wo_b = (const float*)d_in[8];
  const float* ep_w = (const float*)d_in[9];
  const float* ep_b = (const float*)d_in[10];
  const float* ln_g = (const float*)d_in[11];
  const float* ln_b = (const float*)d_in[12];
  float* out = (float*)d_out;

  ushort* Qb    = (ushort*)d_ws;             // 1024*256
  ushort* Kb    = Qb    + 262144;            // 2048*256
  ushort* Vb    = Kb    + 524288;            // 2048*256
  ushort* qepb  = Vb    + 524288;            // 1024*512
  ushort* ctxVp = qepb  + 524288;            // 8192*256
  ushort* attEp = ctxVp + 2097152;           // 8192*512
  float*  S_p   = (float*)(attEp + 4194304); // 8192*8

  proj3_kernel<<<640, 256, 0, stream>>>(q, k, v, wq, wk, wv, ep_w, Qb, Kb, Vb, qepb);
  attn_part_kernel<<<2048, 256, 0, stream>>>(Qb, Kb, Vb, qepb, edge,
                                             ctxVp, attEp, S_p);
  reduce_outln_kernel<<<512, 256, 0, stream>>>(ctxVp, attEp, S_p, ep_w, ep_b,
                                               wo_w, wo_b, q, ln_g, ln_b, out);
}